// Round 5
// baseline (281.157 us; speedup 1.0000x reference)
//
#include <hip/hip_runtime.h>
#include <cmath>

#define NN 64
#define CC 256
#define TT 64
#define VV 25
#define OO 512     // 2*out_planes
#define GG 8
#define NV (NN*VV)   // 1600 elements per channel for qkv/so BN
#define STK 625      // V*V

typedef float f4 __attribute__((ext_vector_type(4)));

// ---------------- kernel 1: y[n,c,v] = mean_t x[n,c,t,v]  (+ zero stat accums) ----------------
__global__ __launch_bounds__(256) void k_mean(const float* __restrict__ x,
                                              float* __restrict__ y,
                                              float* __restrict__ accz) {
    __shared__ float tile[TT * VV];   // 1600 floats
    __shared__ float part[8][VV];
    int b = blockIdx.x;               // n*CC + c
    if (b == 0) {
        // zero qacc(1024) | sacc(4*48=192) | oacc(1024) = 2240 floats (contiguous)
        for (int i = threadIdx.x; i < 2240; i += 256) accz[i] = 0.f;
    }
    const float4* x4 = (const float4*)(x + (size_t)b * (TT * VV));
    float4* t4 = (float4*)tile;
    for (int i = threadIdx.x; i < (TT * VV) / 4; i += 256) t4[i] = x4[i];
    __syncthreads();
    int t = threadIdx.x;
    if (t < 200) {                    // 25 v * 8 t-chunks
        int v = t % VV, ch = t / VV;
        float s = 0.f;
        #pragma unroll
        for (int k = 0; k < 8; ++k) s += tile[(ch * 8 + k) * VV + v];
        part[ch][v] = s;
    }
    __syncthreads();
    if (t < VV) {
        float s = 0.f;
        #pragma unroll
        for (int k = 0; k < 8; ++k) s += part[k][t];
        y[(size_t)b * VV + t] = s * (1.0f / TT);
    }
}

// ---------------- kernel 2: qkv gemm + channel stats atomics ----------------
// grid = NN*8; block handles one n and a 64-wide o-chunk.
__global__ __launch_bounds__(256) void k_qkv(const float* __restrict__ y,
                                             const float* __restrict__ w,
                                             float* __restrict__ qkv,
                                             float* __restrict__ qacc) {
    __shared__ float ys[CC][VV + 1];  // stride 26 -> conflict-free scalar reads
    __shared__ float qs[64][VV + 1];
    int n = blockIdx.x >> 3, oc = blockIdx.x & 7;
    const float* yp = y + (size_t)n * CC * VV;
    for (int i = threadIdx.x; i < CC * VV; i += 256) ys[i / VV][i % VV] = yp[i];
    __syncthreads();
    int t = threadIdx.x;
    if (t < 200) {                    // 200 = 8 o-slots * 25 v
        int v = t % VV, o0 = t / VV;  // o0 in 0..7
        const float* wp = w + (size_t)(oc * 64 + o0) * CC;
        float acc[8] = {0, 0, 0, 0, 0, 0, 0, 0};
        for (int c = 0; c < CC; c += 8) {
            float y0 = ys[c][v],     y1 = ys[c + 1][v], y2 = ys[c + 2][v], y3 = ys[c + 3][v];
            float y4_ = ys[c + 4][v], y5 = ys[c + 5][v], y6 = ys[c + 6][v], y7 = ys[c + 7][v];
            #pragma unroll
            for (int u = 0; u < 8; ++u) {
                const float4 wa = *(const float4*)(wp + (size_t)u * 8 * CC + c);
                const float4 wb = *(const float4*)(wp + (size_t)u * 8 * CC + c + 4);
                acc[u] += y0 * wa.x + y1 * wa.y + y2 * wa.z + y3 * wa.w
                        + y4_ * wb.x + y5 * wb.y + y6 * wb.z + y7 * wb.w;
            }
        }
        #pragma unroll
        for (int u = 0; u < 8; ++u) qs[o0 + u * 8][v] = acc[u];
    }
    __syncthreads();
    // coalesced global write of the 64x25 tile
    float* qp = qkv + ((size_t)n * OO + oc * 64) * VV;
    for (int i = t; i < 64 * VV; i += 256) qp[i] = qs[i / VV][i % VV];
    // per-channel partial stats -> atomics
    if (t < 64) {
        float s = 0.f, s2 = 0.f;
        #pragma unroll
        for (int v = 0; v < VV; ++v) { float val = qs[t][v]; s += val; s2 += val * val; }
        atomicAdd(&qacc[oc * 64 + t], s);
        atomicAdd(&qacc[512 + oc * 64 + t], s2);
    }
}

// ---------------- kernel 3: sim stats only (no score materialization) ----------------
// grid = NN*GG*4; block (n, g, split) handles ij = split (mod 4). Banked sacc[4][48].
__global__ __launch_bounds__(256) void k_sstats(const float* __restrict__ qkv,
                                                const float* __restrict__ rel,
                                                const float* __restrict__ qacc,
                                                const float* __restrict__ gq,
                                                const float* __restrict__ bq,
                                                float* __restrict__ sacc) {
    int blk = blockIdx.x;
    int n = blk >> 5, r = blk & 31, gb = r >> 2, split = r & 3;
    __shared__ float qs[32][VV + 1];
    __shared__ float rs[32 * 49];
    __shared__ float csc[32], csh[32];
    __shared__ float sred[24];
    int t = threadIdx.x;
    if (t < 32) {
        int ch = gb * 64 + t;
        float m = qacc[ch] * (1.0f / NV);
        float var = qacc[512 + ch] * (1.0f / NV) - m * m;
        float sc = gq[ch] * rsqrtf(var + 1e-5f);
        csc[t] = sc; csh[t] = bq[ch] - m * sc;
    }
    __syncthreads();
    for (int i = t; i < 32 * VV; i += 256) {
        int c = i / VV, v = i - c * VV;
        qs[c][v] = qkv[((size_t)n * OO + gb * 64 + c) * VV + v] * csc[c] + csh[c];
    }
    for (int i = t; i < 32 * 49; i += 256) rs[i] = rel[i];
    __syncthreads();
    float ls0 = 0.f, ls1 = 0.f, ls2 = 0.f, ls3 = 0.f, ls4 = 0.f, ls5 = 0.f;
    for (int idx = t; idx < 157; idx += 256) {
        int ij = split + 4 * idx;
        if (ij < STK) {
            int i = ij / VV, j = ij - (ij / VV) * VV;
            float aqk = 0.f, aqr = 0.f, akr = 0.f;
            #pragma unroll
            for (int c = 0; c < 16; ++c) {
                float qv = qs[c][i], kv = qs[16 + c][j];
                aqk += qv * kv;
                aqr += qv * rs[c * 49 + i - j + 24];
                akr += kv * rs[(16 + c) * 49 + j - i + 24];
            }
            ls0 += aqk; ls1 += aqk * aqk;
            ls2 += aqr; ls3 += aqr * aqr;
            ls4 += akr; ls5 += akr * akr;
        }
    }
    #pragma unroll
    for (int off = 32; off > 0; off >>= 1) {
        ls0 += __shfl_down(ls0, off); ls1 += __shfl_down(ls1, off);
        ls2 += __shfl_down(ls2, off); ls3 += __shfl_down(ls3, off);
        ls4 += __shfl_down(ls4, off); ls5 += __shfl_down(ls5, off);
    }
    int lane = t & 63, wid = t >> 6;
    if (lane == 0) {
        sred[wid * 6 + 0] = ls0; sred[wid * 6 + 1] = ls1;
        sred[wid * 6 + 2] = ls2; sred[wid * 6 + 3] = ls3;
        sred[wid * 6 + 4] = ls4; sred[wid * 6 + 5] = ls5;
    }
    __syncthreads();
    if (t < 6) {
        float t2 = sred[t] + sred[6 + t] + sred[12 + t] + sred[18 + t];
        int ch = (t >> 1) * 8 + gb;          // 0:qk(g) 1:qr(8+g) 2:kr(16+g)
        atomicAdd(&sacc[split * 48 + (t & 1) * 24 + ch], t2);
    }
}

// ---------------- kernel 4: recompute scores -> scaled-sum -> softmax -> sv/sve + out stats ----------------
// Softmax is shift-invariant; sim-BN shifts are constant per map -> only scales needed.
__global__ __launch_bounds__(256) void k_attnout(const float* __restrict__ qkv,
                                                 const float* __restrict__ rel,
                                                 const float* __restrict__ qacc,
                                                 const float* __restrict__ gq,
                                                 const float* __restrict__ bq,
                                                 const float* __restrict__ sacc,
                                                 const float* __restrict__ gs,
                                                 float* __restrict__ so,
                                                 float* __restrict__ oacc) {
    int n = blockIdx.x >> 3, gb = blockIdx.x & 7;
    __shared__ float S[STK];
    __shared__ float qk_s[64][VV + 1];     // q(0..15), k(16..31), v(32..63) BN'd
    __shared__ float rs[64 * 49];          // full relative embedding
    __shared__ float svs[800], sves[800];
    __shared__ float csc[64], csh[64];
    __shared__ float simp[3];
    int t = threadIdx.x;
    if (t < 64) {
        int ch = gb * 64 + t;
        float m = qacc[ch] * (1.0f / NV);
        float var = qacc[512 + ch] * (1.0f / NV) - m * m;
        float sc = gq[ch] * rsqrtf(var + 1e-5f);
        csc[t] = sc; csh[t] = bq[ch] - m * sc;
    }
    if (t >= 64 && t < 67) {
        int k = t - 64;
        int ch = k * 8 + gb;
        float s = 0.f, s2 = 0.f;
        #pragma unroll
        for (int bnk = 0; bnk < 4; ++bnk) {
            s  += sacc[bnk * 48 + ch];
            s2 += sacc[bnk * 48 + 24 + ch];
        }
        float m = s * (1.0f / 40000.0f);
        float var = s2 * (1.0f / 40000.0f) - m * m;
        simp[k] = gs[ch] * rsqrtf(var + 1e-5f);
    }
    __syncthreads();
    for (int i = t; i < 64 * VV; i += 256) {
        int c = i / VV, v = i - (i / VV) * VV;
        qk_s[c][v] = qkv[((size_t)n * OO + gb * 64 + c) * VV + v] * csc[c] + csh[c];
    }
    for (int i = t; i < 64 * 49; i += 256) rs[i] = rel[i];
    __syncthreads();
    float s0 = simp[0], s1 = simp[1], s2 = simp[2];
    for (int ij = t; ij < STK; ij += 256) {
        int i = ij / VV, j = ij - (ij / VV) * VV;
        float aqk = 0.f, aqr = 0.f, akr = 0.f;
        #pragma unroll
        for (int c = 0; c < 16; ++c) {
            float qv = qk_s[c][i], kv = qk_s[16 + c][j];
            aqk += qv * kv;
            aqr += qv * rs[c * 49 + i - j + 24];
            akr += kv * rs[(16 + c) * 49 + j - i + 24];
        }
        S[ij] = aqk * s0 + aqr * s1 + akr * s2;
    }
    __syncthreads();
    // wave-parallel softmax: 25 rows x 8 lanes
    if (t < 200) {
        int i = t >> 3, l = t & 7;
        float mx = -1e30f;
        for (int j = l; j < VV; j += 8) mx = fmaxf(mx, S[i * VV + j]);
        #pragma unroll
        for (int off = 4; off > 0; off >>= 1) mx = fmaxf(mx, __shfl_xor(mx, off));
        float sum = 0.f;
        for (int j = l; j < VV; j += 8) {
            float e = expf(S[i * VV + j] - mx);
            S[i * VV + j] = e;
            sum += e;
        }
        #pragma unroll
        for (int off = 4; off > 0; off >>= 1) sum += __shfl_xor(sum, off);
        float inv = 1.0f / sum;
        for (int j = l; j < VV; j += 8) S[i * VV + j] *= inv;
    }
    __syncthreads();
    for (int idx = t; idx < 800; idx += 256) {
        int c = idx / VV, i = idx - (idx / VV) * VV;
        float sv = 0.f, sve = 0.f;
        #pragma unroll
        for (int j = 0; j < VV; ++j) {
            float p = S[i * VV + j];
            sv  += p * qk_s[32 + c][j];
            sve += p * rs[(32 + c) * 49 + i - j + 24];
        }
        svs[idx] = sv; sves[idx] = sve;
    }
    __syncthreads();
    if (t < 64) {
        int c = t >> 1;
        const float* src = (t & 1) ? (sves + c * VV) : (svs + c * VV);
        float s = 0.f, sq = 0.f;
        #pragma unroll
        for (int i = 0; i < VV; ++i) { float val = src[i]; s += val; sq += val * val; }
        atomicAdd(&oacc[gb * 64 + t], s);          // channel = g*64 + 2c + (t&1)
        atomicAdd(&oacc[512 + gb * 64 + t], sq);
    }
    float* sop = so + ((size_t)n * OO + gb * 64) * VV;   // 1600 contiguous floats
    for (int idx = t; idx < 1600; idx += 256) {
        int oc = idx / VV, i = idx - (idx / VV) * VV;
        int c = oc >> 1;
        sop[idx] = (oc & 1) ? sves[c * VV + i] : svs[c * VV + i];
    }
}

// ---------------- kernel 5: out = x * (1 + sigmoid(bn(so[2p]) + bn(so[2p+1]))) ----------------
// Reverse block order: start on the x-tail still resident in L3 from k_mean.
// Non-temporal out stores (write-once) keep x resident in L3.
__global__ __launch_bounds__(256) void k_final(const float* __restrict__ x,
                                               const float* __restrict__ so,
                                               const float* __restrict__ oacc,
                                               const float* __restrict__ go,
                                               const float* __restrict__ bo,
                                               float* __restrict__ out) {
    int b = (NN * CC - 1) - blockIdx.x;    // n*CC + p, reversed
    int n = b >> 8, p = b & 255;
    __shared__ float orow[VV];
    if (threadIdx.x < VV) {
        int o0 = 2 * p, o1 = 2 * p + 1;
        float m0 = oacc[o0] * (1.0f / NV);
        float var0 = oacc[512 + o0] * (1.0f / NV) - m0 * m0;
        float sc0 = go[o0] * rsqrtf(var0 + 1e-5f), sh0 = bo[o0] - m0 * sc0;
        float m1 = oacc[o1] * (1.0f / NV);
        float var1 = oacc[512 + o1] * (1.0f / NV) - m1 * m1;
        float sc1 = go[o1] * rsqrtf(var1 + 1e-5f), sh1 = bo[o1] - m1 * sc1;
        int v = threadIdx.x;
        float a  = so[((size_t)n * OO + o0) * VV + v] * sc0 + sh0;
        float c2 = so[((size_t)n * OO + o1) * VV + v] * sc1 + sh1;
        float z = a + c2;
        orow[v] = 1.0f + 1.0f / (1.0f + expf(-z));
    }
    __syncthreads();
    const f4* x4 = (const f4*)(x + (size_t)b * (TT * VV));
    f4* y4 = (f4*)(out + (size_t)b * (TT * VV));
    for (int wv = threadIdx.x; wv < (TT * VV) / 4; wv += 256) {
        f4 xv = __builtin_nontemporal_load(&x4[wv]);
        int e = 4 * wv;
        int v0 = e % VV;
        f4 r;
        int v;
        v = v0;                      r.x = xv.x * orow[v];
        v = v0 + 1; if (v >= VV) v -= VV; r.y = xv.y * orow[v];
        v = v0 + 2; if (v >= VV) v -= VV; r.z = xv.z * orow[v];
        v = v0 + 3; if (v >= VV) v -= VV; r.w = xv.w * orow[v];
        __builtin_nontemporal_store(r, &y4[wv]);
    }
}

extern "C" void kernel_launch(void* const* d_in, const int* in_sizes, int n_in,
                              void* d_out, int out_size, void* d_ws, size_t ws_size,
                              hipStream_t stream) {
    (void)in_sizes; (void)n_in; (void)out_size; (void)ws_size;
    const float* x        = (const float*)d_in[0];
    const float* w_qkv    = (const float*)d_in[1];
    const float* relative = (const float*)d_in[2];
    const float* bn_qkv_g = (const float*)d_in[3];
    const float* bn_qkv_b = (const float*)d_in[4];
    const float* bn_sim_g = (const float*)d_in[5];
    const float* bn_sim_b = (const float*)d_in[6];
    const float* bn_out_g = (const float*)d_in[7];
    const float* bn_out_b = (const float*)d_in[8];
    (void)bn_sim_b;   // sim-BN shifts are softmax-invariant
    float* out = (float*)d_out;

    float* ws = (float*)d_ws;
    float* w_y    = ws;                 // NN*CC*VV = 409600
    float* w_qkvp = ws + 409600;        // NN*OO*VV = 819200
    float* w_so   = ws + 1228800;       // NN*OO*VV = 819200
    float* qacc   = ws + 2048000;       // 1024 (sum | sumsq per 512 ch)
    float* sacc   = qacc + 1024;        // 4 banks x 48 (24 sums | 24 sumsq)
    float* oacc   = sacc + 192;         // 1024

    k_mean<<<NN * CC, 256, 0, stream>>>(x, w_y, qacc);
    k_qkv<<<NN * 8, 256, 0, stream>>>(w_y, w_qkv, w_qkvp, qacc);
    k_sstats<<<NN * GG * 4, 256, 0, stream>>>(w_qkvp, relative, qacc, bn_qkv_g, bn_qkv_b, sacc);
    k_attnout<<<NN * GG, 256, 0, stream>>>(w_qkvp, relative, qacc, bn_qkv_g, bn_qkv_b,
                                           sacc, bn_sim_g, w_so, oacc);
    k_final<<<NN * CC, 256, 0, stream>>>(x, w_so, oacc, bn_out_g, bn_out_b, out);
}